// Round 24
// baseline (97.141 us; speedup 1.0000x reference)
//
#include <hip/hip_runtime.h>
#include <hip/hip_bf16.h>
#include <stdint.h>

typedef __attribute__((ext_vector_type(8))) short bf16x8;
typedef __attribute__((ext_vector_type(4))) float f32x4;

// ALL-REGISTER transformer block, TWO pairs (tiles A,B) per wave, 512-thread
// blocks, C-operand bias folds, external weight pre-pack, double-buffered x
// prefetch, minimal fences, and T5 s_setprio around MFMA clusters (this
// round's single change vs r23).
//
// T5 applicability: our main loop has NO block barrier -- the 8 waves/CU
// free-run and drift across phases (guide m191: setprio +4-7% in exactly
// this non-lockstep regime; m190: only hurts barrier-lockstep GEMM).
// setprio(1) around MFMA-dense clusters lets the CU scheduler favor the
// MFMA-issuing wave while its SIMD partner runs VALU/pack.
//
// Transposed-chaining math identical to rounds 9-23 (PASSED, absmax 0.031):
// k = 8*fg+j <-> logical c = 16*(2m+u)+4*fg+(j&3), u=j>>2, applied to both
// register tiles and the weight pre-pack. x ownership: lane(fr,fg) owns row
// fr, cols 16*nt+4*fg+r. Each f32x4 global access covers 16 full 64-B
// sectors -> fully coalesced.
//
// d_ws layout (and LDS copy, byte-identical):
//   [0, 98304)  96 weight fragments, bf16, frag f at byte f*1024 + lane*16:
//     f 0..23: QKV (f = sel*8 + hd*2 + m)   f 24..31: Wp^T
//     f 32..63: W1^T (f = 32 + t*2 + m)     f 64..95: W2^T (f = 64 + nt*8 + m)
//   [98304, 100864) params f32: g1@0 be1@64 g2@128 be2@192 bp@256 b2@320 b1@384

static __device__ __forceinline__ unsigned short f2bf(float f) {
    union { __hip_bfloat16 h; unsigned short u; } cv;
    cv.h = __float2bfloat16(f);
    return cv.u;
}
static __device__ __forceinline__ unsigned int f2bf2(float a, float b) {
    return (unsigned int)f2bf(a) | ((unsigned int)f2bf(b) << 16);
}
static __device__ __forceinline__ bf16x8 mk8(uint2 a, uint2 b) {
    union { uint4 u; bf16x8 v; } c;
    c.u = make_uint4(a.x, a.y, b.x, b.y);
    return c.v;
}
static __device__ __forceinline__ uint2 packbf(f32x4 a) {
    return make_uint2(f2bf2(a[0], a[1]), f2bf2(a[2], a[3]));
}
static __device__ __forceinline__ uint2 lnq(f32x4 x, float mu, float inv, f32x4 g, f32x4 b) {
    return make_uint2(f2bf2((x[0]-mu)*inv*g[0]+b[0], (x[1]-mu)*inv*g[1]+b[1]),
                      f2bf2((x[2]-mu)*inv*g[2]+b[2], (x[3]-mu)*inv*g[3]+b[3]));
}
static __device__ __forceinline__ uint2 relupack0(f32x4 a) {
    return make_uint2(f2bf2(fmaxf(a[0],0.f), fmaxf(a[1],0.f)),
                      f2bf2(fmaxf(a[2],0.f), fmaxf(a[3],0.f)));
}

#define MFMA(A,B,C) __builtin_amdgcn_mfma_f32_16x16x32_bf16((A),(B),(C),0,0,0)
#define SB() __builtin_amdgcn_sched_barrier(0)
#define PRIO1() __builtin_amdgcn_s_setprio(1)
#define PRIO0() __builtin_amdgcn_s_setprio(0)

// QK^T scores -> masked exp (no max-sub: |s|<~2 by construction) -> PV.
static __device__ __forceinline__ uint2 attn_tail(f32x4 sa, uint2 vw, int fr, int fg) {
    const f32x4 zf = {0.f,0.f,0.f,0.f};
    const uint2 z2 = make_uint2(0u,0u);
    int tk0 = 4*fg, frq = fr & 7;
    bool v8 = ((fr ^ tk0) & 8) == 0;
    float p0 = (v8 && (((tk0+0)&7) <= frq)) ? __expf(sa[0]*0.125f) : 0.f;
    float p1 = (v8 && (((tk0+1)&7) <= frq)) ? __expf(sa[1]*0.125f) : 0.f;
    float p2 = (v8 && (((tk0+2)&7) <= frq)) ? __expf(sa[2]*0.125f) : 0.f;
    float p3 = (v8 && (((tk0+3)&7) <= frq)) ? __expf(sa[3]*0.125f) : 0.f;
    float rsum = p0 + p1 + p2 + p3;
    rsum += __shfl_xor(rsum, 16, 64);
    rsum += __shfl_xor(rsum, 32, 64);
    float pinv = __builtin_amdgcn_rcpf(rsum);
    uint2 pb = make_uint2(f2bf2(p0,p1), f2bf2(p2,p3));
    PRIO1();
    f32x4 oa = MFMA(mk8(vw, z2), mk8(pb, z2), zf);
    PRIO0();
    return make_uint2(f2bf2(oa[0]*pinv, oa[1]*pinv), f2bf2(oa[2]*pinv, oa[3]*pinv));
}

// One head, both tiles; weight frags loaded once at call site, used 2x.
static __device__ __forceinline__ void attn_head2(
    bf16x8 wq0, bf16x8 wq1, bf16x8 wk0, bf16x8 wk1, bf16x8 wv0, bf16x8 wv1,
    bf16x8 hA0, bf16x8 hA1, bf16x8 hB0, bf16x8 hB1, int fr, int fg,
    uint2& oA, uint2& oB)
{
    const f32x4 zf = {0.f,0.f,0.f,0.f};
    const uint2 z2 = make_uint2(0u,0u);
    {   // tile A
        PRIO1();
        f32x4 qa = MFMA(wq0, hA0, zf); qa = MFMA(wq1, hA1, qa);
        f32x4 ka = MFMA(wk0, hA0, zf); ka = MFMA(wk1, hA1, ka);
        f32x4 va = MFMA(hA0, wv0, zf); va = MFMA(hA1, wv1, va);
        PRIO0();
        uint2 qw = packbf(qa), kw = packbf(ka), vw = packbf(va);
        PRIO1();
        f32x4 sa = MFMA(mk8(kw, z2), mk8(qw, z2), zf);
        PRIO0();
        oA = attn_tail(sa, vw, fr, fg);
    }
    {   // tile B
        PRIO1();
        f32x4 qa = MFMA(wq0, hB0, zf); qa = MFMA(wq1, hB1, qa);
        f32x4 ka = MFMA(wk0, hB0, zf); ka = MFMA(wk1, hB1, ka);
        f32x4 va = MFMA(hB0, wv0, zf); va = MFMA(hB1, wv1, va);
        PRIO0();
        uint2 qw = packbf(qa), kw = packbf(ka), vw = packbf(va);
        PRIO1();
        f32x4 sa = MFMA(mk8(kw, z2), mk8(qw, z2), zf);
        PRIO0();
        oB = attn_tail(sa, vw, fr, fg);
    }
}

// ---- helper kernel: pack weights + params into d_ws (run every launch) ----
__global__ __launch_bounds__(512)
void pack_weights(const float* __restrict__ Wq, const float* __restrict__ Wk,
                  const float* __restrict__ Wv, const float* __restrict__ Wp,
                  const float* __restrict__ W1, const float* __restrict__ W2,
                  const float* __restrict__ bp, const float* __restrict__ b1,
                  const float* __restrict__ b2, const float* __restrict__ g1,
                  const float* __restrict__ be1, const float* __restrict__ g2,
                  const float* __restrict__ be2, unsigned short* __restrict__ gw)
{
    int e = blockIdx.x * 512 + threadIdx.x;
    if (e < 49152) {
        int j = e & 7, ln = (e >> 3) & 63, f = e >> 9;
        int fr_ = ln & 15, fg_ = ln >> 4;
        int u = j >> 2, r_ = j & 3;
        float src;
        if (f < 24) {                 // QKV: f = sel*8 + hd*2 + m
            int sel = f >> 3, hd = (f >> 1) & 3, m = f & 1;
            int c = 16*(2*m + u) + 4*fg_ + r_;
            const float* W = (sel == 0) ? Wq : ((sel == 1) ? Wk : Wv);
            src = W[hd*1024 + c*16 + fr_];
        } else if (f < 32) {          // Wp^T
            int t = f - 24, nt = t >> 1, m = t & 1;
            int d = 16*(2*m + u) + 4*fg_ + r_;
            src = Wp[d*64 + 16*nt + fr_];
        } else if (f < 64) {          // W1^T
            int t = f - 32, tt = t >> 1, m = t & 1;
            int c = 16*(2*m + u) + 4*fg_ + r_;
            src = W1[c*256 + 16*tt + fr_];
        } else {                      // W2^T
            int t = f - 64, nt = t >> 3, m = t & 7;
            int n1 = 16*(2*m + u) + 4*fg_ + r_;
            src = W2[n1*64 + 16*nt + fr_];
        }
        gw[e] = f2bf(src);
    } else {
        int t = e - 49152;
        if (t < 640) {
            float v;
            if      (t < 64)  v = g1[t];
            else if (t < 128) v = be1[t - 64];
            else if (t < 192) v = g2[t - 128];
            else if (t < 256) v = be2[t - 192];
            else if (t < 320) v = bp[t - 256];
            else if (t < 384) v = b2[t - 320];
            else              v = b1[t - 384];
            ((float*)(gw + 49152))[t] = v;
        }
    }
}

__global__ __launch_bounds__(512, 1)
void fused_block(const unsigned short* __restrict__ gw,
                 const float* __restrict__ xg, float* __restrict__ out,
                 int nPairsTotal)
{
    __shared__ __align__(16) unsigned char LDS[100864];

    const int tid  = threadIdx.x;
    const int lane = tid & 63;
    const int wid  = tid >> 6;        // 0..7
    const int fr   = lane & 15;
    const int fg   = lane >> 4;

    // ---- coalesced LDS fill: 100864 B = 6304 uint4 = 12*512 + 160 ----
    {
        const uint4* src = (const uint4*)gw;
        uint4* dst = (uint4*)LDS;
        #pragma unroll
        for (int k = 0; k < 12; ++k)
            dst[tid + 512*k] = src[tid + 512*k];
        if (tid < 160) dst[tid + 6144] = src[tid + 6144];
    }
    __syncthreads();

    const float* PG = (const float*)(LDS + 98304);
    #define WFL(F) (*(const bf16x8*)(LDS + ((F) << 10) + (lane << 4)))
    #define PG4(I) (*(const f32x4*)(PG + (I) + 4*fg))

    const int pipe = blockIdx.x * 8 + wid;    // 256*8 = 2048 pipes
    const f32x4 zf = {0.f, 0.f, 0.f, 0.f};
    const int xoff = fr*64 + 4*fg;
    const int nP2 = nPairsTotal >> 1;         // pair-pairs (16384)

    // prologue: prefetch first tile pair
    f32x4 nA0, nA1, nA2, nA3, nB0, nB1, nB2, nB3;
    if (pipe < nP2) {
        const float* xb0 = xg + (size_t)pipe * 2048;
        nA0 = *(const f32x4*)(xb0 + xoff);
        nA1 = *(const f32x4*)(xb0 + xoff + 16);
        nA2 = *(const f32x4*)(xb0 + xoff + 32);
        nA3 = *(const f32x4*)(xb0 + xoff + 48);
        nB0 = *(const f32x4*)(xb0 + 1024 + xoff);
        nB1 = *(const f32x4*)(xb0 + 1024 + xoff + 16);
        nB2 = *(const f32x4*)(xb0 + 1024 + xoff + 32);
        nB3 = *(const f32x4*)(xb0 + 1024 + xoff + 48);
    }

    #pragma unroll 1
    for (int gp2 = pipe; gp2 < nP2; gp2 += 2048) {
        float* obp = out + (size_t)gp2 * 2048;

        f32x4 xA0 = nA0, xA1 = nA1, xA2 = nA2, xA3 = nA3;
        f32x4 xB0 = nB0, xB1 = nB1, xB2 = nB2, xB3 = nB3;

        {   // issue next-tile prefetch; stays in flight across the iteration
            int gpn = gp2 + 2048;
            if (gpn < nP2) {
                const float* xbn = xg + (size_t)gpn * 2048;
                nA0 = *(const f32x4*)(xbn + xoff);
                nA1 = *(const f32x4*)(xbn + xoff + 16);
                nA2 = *(const f32x4*)(xbn + xoff + 32);
                nA3 = *(const f32x4*)(xbn + xoff + 48);
                nB0 = *(const f32x4*)(xbn + 1024 + xoff);
                nB1 = *(const f32x4*)(xbn + 1024 + xoff + 16);
                nB2 = *(const f32x4*)(xbn + 1024 + xoff + 32);
                nB3 = *(const f32x4*)(xbn + 1024 + xoff + 48);
            }
        }
        SB();   // keep prefetch issue pinned early

        #define ACC4(S,SS,V) { S += V[0]+V[1]+V[2]+V[3]; \
                               SS += V[0]*V[0]+V[1]*V[1]+V[2]*V[2]+V[3]*V[3]; }

        // ---- LN1 (shared params) -> h fragments for A and B ----
        bf16x8 hA0, hA1, hB0, hB1;
        {
            float sA=0.f, qA=0.f, sB=0.f, qB=0.f;
            ACC4(sA,qA,xA0); ACC4(sA,qA,xA1); ACC4(sA,qA,xA2); ACC4(sA,qA,xA3);
            ACC4(sB,qB,xB0); ACC4(sB,qB,xB1); ACC4(sB,qB,xB2); ACC4(sB,qB,xB3);
            sA += __shfl_xor(sA,16,64); qA += __shfl_xor(qA,16,64);
            sA += __shfl_xor(sA,32,64); qA += __shfl_xor(qA,32,64);
            sB += __shfl_xor(sB,16,64); qB += __shfl_xor(qB,16,64);
            sB += __shfl_xor(sB,32,64); qB += __shfl_xor(qB,32,64);
            float muA = sA*0.015625f, invA = rsqrtf(qA*0.015625f - muA*muA + 1e-5f);
            float muB = sB*0.015625f, invB = rsqrtf(qB*0.015625f - muB*muB + 1e-5f);
            hA0 = mk8(lnq(xA0,muA,invA,PG4(0),  PG4(64)),
                      lnq(xA1,muA,invA,PG4(16), PG4(80)));
            hA1 = mk8(lnq(xA2,muA,invA,PG4(32), PG4(96)),
                      lnq(xA3,muA,invA,PG4(48), PG4(112)));
            hB0 = mk8(lnq(xB0,muB,invB,PG4(0),  PG4(64)),
                      lnq(xB1,muB,invB,PG4(16), PG4(80)));
            hB1 = mk8(lnq(xB2,muB,invB,PG4(32), PG4(96)),
                      lnq(xB3,muB,invB,PG4(48), PG4(112)));
        }

        // ---- attention: 4 heads; single mid-point fence ----
        uint2 oA0,oA1,oA2,oA3, oB0,oB1,oB2,oB3;
        attn_head2(WFL(0), WFL(1), WFL(8),  WFL(9),  WFL(16), WFL(17),
                   hA0,hA1, hB0,hB1, fr, fg, oA0, oB0);
        attn_head2(WFL(2), WFL(3), WFL(10), WFL(11), WFL(18), WFL(19),
                   hA0,hA1, hB0,hB1, fr, fg, oA1, oB1);
        SB();   // caps transient frag pressure (r18-proven window)
        attn_head2(WFL(4), WFL(5), WFL(12), WFL(13), WFL(20), WFL(21),
                   hA0,hA1, hB0,hB1, fr, fg, oA2, oB2);
        attn_head2(WFL(6), WFL(7), WFL(14), WFL(15), WFL(22), WFL(23),
                   hA0,hA1, hB0,hB1, fr, fg, oA3, oB3);

        // ---- proj: C-init = xv + bp; result becomes new xv (residual 1) ----
        {
            bf16x8 olo = mk8(oA0,oA1), ohi = mk8(oA2,oA3);
            bf16x8 plo = mk8(oB0,oB1), phi = mk8(oB2,oB3);
            #define PROJ(NT, XA, XB) { \
                f32x4 bv = PG4(256 + 16*(NT)); \
                f32x4 ca, cb; \
                ca[0]=XA[0]+bv[0]; ca[1]=XA[1]+bv[1]; ca[2]=XA[2]+bv[2]; ca[3]=XA[3]+bv[3]; \
                cb[0]=XB[0]+bv[0]; cb[1]=XB[1]+bv[1]; cb[2]=XB[2]+bv[2]; cb[3]=XB[3]+bv[3]; \
                bf16x8 wp0 = WFL(24+(NT)*2+0), wp1 = WFL(24+(NT)*2+1); \
                PRIO1(); \
                f32x4 pa = MFMA(wp0, olo, ca); pa = MFMA(wp1, ohi, pa); \
                f32x4 pb = MFMA(wp0, plo, cb); pb = MFMA(wp1, phi, pb); \
                PRIO0(); \
                XA = pa; XB = pb; }
            PROJ(0, xA0, xB0); PROJ(1, xA1, xB1); PROJ(2, xA2, xB2); PROJ(3, xA3, xB3);
            #undef PROJ
        }

        // ---- LN2 -> h2 frags; then fa C-init = xv + b2 (xv dies here) ----
        bf16x8 cA0, cA1, cB0, cB1;
        f32x4 fA0, fA1, fA2, fA3, fB0, fB1, fB2, fB3;
        {
            float sA=0.f, qA=0.f, sB=0.f, qB=0.f;
            ACC4(sA,qA,xA0); ACC4(sA,qA,xA1); ACC4(sA,qA,xA2); ACC4(sA,qA,xA3);
            ACC4(sB,qB,xB0); ACC4(sB,qB,xB1); ACC4(sB,qB,xB2); ACC4(sB,qB,xB3);
            sA += __shfl_xor(sA,16,64); qA += __shfl_xor(qA,16,64);
            sA += __shfl_xor(sA,32,64); qA += __shfl_xor(qA,32,64);
            sB += __shfl_xor(sB,16,64); qB += __shfl_xor(qB,16,64);
            sB += __shfl_xor(sB,32,64); qB += __shfl_xor(qB,32,64);
            float muA = sA*0.015625f, invA = rsqrtf(qA*0.015625f - muA*muA + 1e-5f);
            float muB = sB*0.015625f, invB = rsqrtf(qB*0.015625f - muB*muB + 1e-5f);
            cA0 = mk8(lnq(xA0,muA,invA,PG4(128), PG4(192)),
                      lnq(xA1,muA,invA,PG4(144), PG4(208)));
            cA1 = mk8(lnq(xA2,muA,invA,PG4(160), PG4(224)),
                      lnq(xA3,muA,invA,PG4(176), PG4(240)));
            cB0 = mk8(lnq(xB0,muB,invB,PG4(128), PG4(192)),
                      lnq(xB1,muB,invB,PG4(144), PG4(208)));
            cB1 = mk8(lnq(xB2,muB,invB,PG4(160), PG4(224)),
                      lnq(xB3,muB,invB,PG4(176), PG4(240)));
            #define FINIT(NT, FA, FB, XA, XB) { \
                f32x4 bv = PG4(320 + 16*(NT)); \
                FA[0]=XA[0]+bv[0]; FA[1]=XA[1]+bv[1]; FA[2]=XA[2]+bv[2]; FA[3]=XA[3]+bv[3]; \
                FB[0]=XB[0]+bv[0]; FB[1]=XB[1]+bv[1]; FB[2]=XB[2]+bv[2]; FB[3]=XB[3]+bv[3]; }
            FINIT(0, fA0, fB0, xA0, xB0); FINIT(1, fA1, fB1, xA1, xB1);
            FINIT(2, fA2, fB2, xA2, xB2); FINIT(3, fA3, fB3, xA3, xB3);
            #undef FINIT
        }

        // ---- MLP: W1 C-init = b1; accumulate into fa (already xv+b2).
        //      unroll-1 loop self-fences; no SB inside. ----
        #pragma unroll 1
        for (int m2 = 0; m2 < 8; ++m2) {
            int t0 = 2*m2, t1 = 2*m2 + 1;
            bf16x8 w10 = WFL(32+t0*2+0), w11 = WFL(32+t0*2+1);
            f32x4 bi0 = PG4(384 + 16*t0);
            PRIO1();
            f32x4 aA = MFMA(w10, cA0, bi0); aA = MFMA(w11, cA1, aA);
            f32x4 aB = MFMA(w10, cB0, bi0); aB = MFMA(w11, cB1, aB);
            PRIO0();
            uint2 frA0 = relupack0(aA), frB0 = relupack0(aB);
            bf16x8 w12 = WFL(32+t1*2+0), w13 = WFL(32+t1*2+1);
            f32x4 bi1 = PG4(384 + 16*t1);
            PRIO1();
            f32x4 cAa = MFMA(w12, cA0, bi1); cAa = MFMA(w13, cA1, cAa);
            f32x4 cBa = MFMA(w12, cB0, bi1); cBa = MFMA(w13, cB1, cBa);
            PRIO0();
            uint2 frA1 = relupack0(cAa), frB1 = relupack0(cBa);
            bf16x8 ffrA = mk8(frA0, frA1), ffrB = mk8(frB0, frB1);
            bf16x8 w20 = WFL(64 + 0*8 + m2);
            bf16x8 w21 = WFL(64 + 1*8 + m2);
            bf16x8 w22 = WFL(64 + 2*8 + m2);
            bf16x8 w23 = WFL(64 + 3*8 + m2);
            PRIO1();
            fA0 = MFMA(w20, ffrA, fA0); fB0 = MFMA(w20, ffrB, fB0);
            fA1 = MFMA(w21, ffrA, fA1); fB1 = MFMA(w21, ffrB, fB1);
            fA2 = MFMA(w22, ffrA, fA2); fB2 = MFMA(w22, ffrB, fB2);
            fA3 = MFMA(w23, ffrA, fA3); fB3 = MFMA(w23, ffrB, fB3);
            PRIO0();
        }

        // ---- store (residual+bias already folded into fa) ----
        *(f32x4*)(obp + xoff)             = fA0;
        *(f32x4*)(obp + xoff + 16)        = fA1;
        *(f32x4*)(obp + xoff + 32)        = fA2;
        *(f32x4*)(obp + xoff + 48)        = fA3;
        *(f32x4*)(obp + 1024 + xoff)      = fB0;
        *(f32x4*)(obp + 1024 + xoff + 16) = fB1;
        *(f32x4*)(obp + 1024 + xoff + 32) = fB2;
        *(f32x4*)(obp + 1024 + xoff + 48) = fB3;
        #undef ACC4
    }
    #undef WFL
    #undef PG4
}

extern "C" void kernel_launch(void* const* d_in, const int* in_sizes, int n_in,
                              void* d_out, int out_size, void* d_ws, size_t ws_size,
                              hipStream_t stream) {
    const float* x   = (const float*)d_in[0];
    const float* Wq  = (const float*)d_in[1];
    const float* Wk  = (const float*)d_in[2];
    const float* Wv  = (const float*)d_in[3];
    const float* Wp  = (const float*)d_in[4];
    const float* bp  = (const float*)d_in[5];
    const float* W1  = (const float*)d_in[6];
    const float* b1  = (const float*)d_in[7];
    const float* W2  = (const float*)d_in[8];
    const float* b2  = (const float*)d_in[9];
    const float* g1  = (const float*)d_in[10];
    const float* be1 = (const float*)d_in[11];
    const float* g2  = (const float*)d_in[12];
    const float* be2 = (const float*)d_in[13];
    unsigned short* gw = (unsigned short*)d_ws;   // 100864 bytes used

    pack_weights<<<dim3(98), dim3(512), 0, stream>>>(
        Wq, Wk, Wv, Wp, W1, W2, bp, b1, b2, g1, be1, g2, be2, gw);

    int nPairs = in_sizes[0] / 1024;   // (B*T*C) / (2*8*64) = 32768
    fused_block<<<dim3(256), dim3(512), 0, stream>>>(
        gw, x, (float*)d_out, nPairs);
}

// Round 25
// 94.986 us; speedup vs baseline: 1.0227x; 1.0227x over previous
//
#include <hip/hip_runtime.h>
#include <hip/hip_bf16.h>
#include <stdint.h>

typedef __attribute__((ext_vector_type(8))) short bf16x8;
typedef __attribute__((ext_vector_type(4))) float f32x4;

// ALL-REGISTER transformer block — FINAL (round 23 configuration, best
// measured: harness 95.5us, rocprof ~107, absmax 0.031).
//
// Structure: TWO pairs (tiles A,B) per wave, 512-thread blocks, MFMA
// C-operand bias folds, external weight pre-pack kernel, double-buffered x
// prefetch, minimal scheduler fences.
//
// Key hard-won constraints (rounds 9-24):
// - VGPR cap = 65536/threads on this toolchain (launch_bounds 2nd arg and
//   amdgpu_waves_per_eu do NOT raise it). Live set must stay under it or
//   the allocator spills loop-carried state -> GB-scale scratch traffic.
// - Pre-RA scheduler hoists ds_read results across phases; sched_barrier(0)
//   fences + unroll-1 MLP bound the hoisting window (r14's 1.4GB lesson).
// - Weight pre-pack must be a separate kernel: in-kernel serial gather-pack
//   cost ~24us/block every launch (r19: -30us).
// - L2 weight streaming (r20/r21) and occupancy raises (r16) all neutral or
//   negative: within-wave dependency chains set the pace at 2 waves/SIMD.
//
// Transposed-chaining math (PASSED rounds 9-24, absmax 0.031):
// every second GEMM computed as Y^T = W^T X^T so MFMA D-registers feed the
// next MFMA directly; k = 8*fg+j <-> logical c = 16*(2m+u)+4*fg+(j&3),
// u=j>>2, applied to register tiles and weight pre-pack alike. x ownership:
// lane(fr,fg) owns row fr, cols 16*nt+4*fg+r; f32x4 accesses fully coalesced.
//
// d_ws layout (and LDS copy, byte-identical):
//   [0, 98304)  96 weight fragments, bf16, frag f at byte f*1024 + lane*16:
//     f 0..23: QKV (f = sel*8 + hd*2 + m)   f 24..31: Wp^T
//     f 32..63: W1^T (f = 32 + t*2 + m)     f 64..95: W2^T (f = 64 + nt*8 + m)
//   [98304, 100864) params f32: g1@0 be1@64 g2@128 be2@192 bp@256 b2@320 b1@384

static __device__ __forceinline__ unsigned short f2bf(float f) {
    union { __hip_bfloat16 h; unsigned short u; } cv;
    cv.h = __float2bfloat16(f);
    return cv.u;
}
static __device__ __forceinline__ unsigned int f2bf2(float a, float b) {
    return (unsigned int)f2bf(a) | ((unsigned int)f2bf(b) << 16);
}
static __device__ __forceinline__ bf16x8 mk8(uint2 a, uint2 b) {
    union { uint4 u; bf16x8 v; } c;
    c.u = make_uint4(a.x, a.y, b.x, b.y);
    return c.v;
}
static __device__ __forceinline__ uint2 packbf(f32x4 a) {
    return make_uint2(f2bf2(a[0], a[1]), f2bf2(a[2], a[3]));
}
static __device__ __forceinline__ uint2 lnq(f32x4 x, float mu, float inv, f32x4 g, f32x4 b) {
    return make_uint2(f2bf2((x[0]-mu)*inv*g[0]+b[0], (x[1]-mu)*inv*g[1]+b[1]),
                      f2bf2((x[2]-mu)*inv*g[2]+b[2], (x[3]-mu)*inv*g[3]+b[3]));
}
static __device__ __forceinline__ uint2 relupack0(f32x4 a) {
    return make_uint2(f2bf2(fmaxf(a[0],0.f), fmaxf(a[1],0.f)),
                      f2bf2(fmaxf(a[2],0.f), fmaxf(a[3],0.f)));
}

#define MFMA(A,B,C) __builtin_amdgcn_mfma_f32_16x16x32_bf16((A),(B),(C),0,0,0)
#define SB() __builtin_amdgcn_sched_barrier(0)

// QK^T scores -> masked exp (no max-sub: |s|<~2 by construction) -> PV.
static __device__ __forceinline__ uint2 attn_tail(f32x4 sa, uint2 vw, int fr, int fg) {
    const f32x4 zf = {0.f,0.f,0.f,0.f};
    const uint2 z2 = make_uint2(0u,0u);
    int tk0 = 4*fg, frq = fr & 7;
    bool v8 = ((fr ^ tk0) & 8) == 0;
    float p0 = (v8 && (((tk0+0)&7) <= frq)) ? __expf(sa[0]*0.125f) : 0.f;
    float p1 = (v8 && (((tk0+1)&7) <= frq)) ? __expf(sa[1]*0.125f) : 0.f;
    float p2 = (v8 && (((tk0+2)&7) <= frq)) ? __expf(sa[2]*0.125f) : 0.f;
    float p3 = (v8 && (((tk0+3)&7) <= frq)) ? __expf(sa[3]*0.125f) : 0.f;
    float rsum = p0 + p1 + p2 + p3;
    rsum += __shfl_xor(rsum, 16, 64);
    rsum += __shfl_xor(rsum, 32, 64);
    float pinv = __builtin_amdgcn_rcpf(rsum);
    uint2 pb = make_uint2(f2bf2(p0,p1), f2bf2(p2,p3));
    f32x4 oa = MFMA(mk8(vw, z2), mk8(pb, z2), zf);
    return make_uint2(f2bf2(oa[0]*pinv, oa[1]*pinv), f2bf2(oa[2]*pinv, oa[3]*pinv));
}

// One head, both tiles; weight frags loaded once at call site, used 2x.
static __device__ __forceinline__ void attn_head2(
    bf16x8 wq0, bf16x8 wq1, bf16x8 wk0, bf16x8 wk1, bf16x8 wv0, bf16x8 wv1,
    bf16x8 hA0, bf16x8 hA1, bf16x8 hB0, bf16x8 hB1, int fr, int fg,
    uint2& oA, uint2& oB)
{
    const f32x4 zf = {0.f,0.f,0.f,0.f};
    const uint2 z2 = make_uint2(0u,0u);
    {   // tile A
        f32x4 qa = MFMA(wq0, hA0, zf); qa = MFMA(wq1, hA1, qa);
        f32x4 ka = MFMA(wk0, hA0, zf); ka = MFMA(wk1, hA1, ka);
        f32x4 va = MFMA(hA0, wv0, zf); va = MFMA(hA1, wv1, va);
        uint2 qw = packbf(qa), kw = packbf(ka), vw = packbf(va);
        f32x4 sa = MFMA(mk8(kw, z2), mk8(qw, z2), zf);
        oA = attn_tail(sa, vw, fr, fg);
    }
    {   // tile B
        f32x4 qa = MFMA(wq0, hB0, zf); qa = MFMA(wq1, hB1, qa);
        f32x4 ka = MFMA(wk0, hB0, zf); ka = MFMA(wk1, hB1, ka);
        f32x4 va = MFMA(hB0, wv0, zf); va = MFMA(hB1, wv1, va);
        uint2 qw = packbf(qa), kw = packbf(ka), vw = packbf(va);
        f32x4 sa = MFMA(mk8(kw, z2), mk8(qw, z2), zf);
        oB = attn_tail(sa, vw, fr, fg);
    }
}

// ---- helper kernel: pack weights + params into d_ws (run every launch) ----
__global__ __launch_bounds__(512)
void pack_weights(const float* __restrict__ Wq, const float* __restrict__ Wk,
                  const float* __restrict__ Wv, const float* __restrict__ Wp,
                  const float* __restrict__ W1, const float* __restrict__ W2,
                  const float* __restrict__ bp, const float* __restrict__ b1,
                  const float* __restrict__ b2, const float* __restrict__ g1,
                  const float* __restrict__ be1, const float* __restrict__ g2,
                  const float* __restrict__ be2, unsigned short* __restrict__ gw)
{
    int e = blockIdx.x * 512 + threadIdx.x;
    if (e < 49152) {
        int j = e & 7, ln = (e >> 3) & 63, f = e >> 9;
        int fr_ = ln & 15, fg_ = ln >> 4;
        int u = j >> 2, r_ = j & 3;
        float src;
        if (f < 24) {                 // QKV: f = sel*8 + hd*2 + m
            int sel = f >> 3, hd = (f >> 1) & 3, m = f & 1;
            int c = 16*(2*m + u) + 4*fg_ + r_;
            const float* W = (sel == 0) ? Wq : ((sel == 1) ? Wk : Wv);
            src = W[hd*1024 + c*16 + fr_];
        } else if (f < 32) {          // Wp^T
            int t = f - 24, nt = t >> 1, m = t & 1;
            int d = 16*(2*m + u) + 4*fg_ + r_;
            src = Wp[d*64 + 16*nt + fr_];
        } else if (f < 64) {          // W1^T
            int t = f - 32, tt = t >> 1, m = t & 1;
            int c = 16*(2*m + u) + 4*fg_ + r_;
            src = W1[c*256 + 16*tt + fr_];
        } else {                      // W2^T
            int t = f - 64, nt = t >> 3, m = t & 7;
            int n1 = 16*(2*m + u) + 4*fg_ + r_;
            src = W2[n1*64 + 16*nt + fr_];
        }
        gw[e] = f2bf(src);
    } else {
        int t = e - 49152;
        if (t < 640) {
            float v;
            if      (t < 64)  v = g1[t];
            else if (t < 128) v = be1[t - 64];
            else if (t < 192) v = g2[t - 128];
            else if (t < 256) v = be2[t - 192];
            else if (t < 320) v = bp[t - 256];
            else if (t < 384) v = b2[t - 320];
            else              v = b1[t - 384];
            ((float*)(gw + 49152))[t] = v;
        }
    }
}

__global__ __launch_bounds__(512, 1)
void fused_block(const unsigned short* __restrict__ gw,
                 const float* __restrict__ xg, float* __restrict__ out,
                 int nPairsTotal)
{
    __shared__ __align__(16) unsigned char LDS[100864];

    const int tid  = threadIdx.x;
    const int lane = tid & 63;
    const int wid  = tid >> 6;        // 0..7
    const int fr   = lane & 15;
    const int fg   = lane >> 4;

    // ---- coalesced LDS fill: 100864 B = 6304 uint4 = 12*512 + 160 ----
    {
        const uint4* src = (const uint4*)gw;
        uint4* dst = (uint4*)LDS;
        #pragma unroll
        for (int k = 0; k < 12; ++k)
            dst[tid + 512*k] = src[tid + 512*k];
        if (tid < 160) dst[tid + 6144] = src[tid + 6144];
    }
    __syncthreads();

    const float* PG = (const float*)(LDS + 98304);
    #define WFL(F) (*(const bf16x8*)(LDS + ((F) << 10) + (lane << 4)))
    #define PG4(I) (*(const f32x4*)(PG + (I) + 4*fg))

    const int pipe = blockIdx.x * 8 + wid;    // 256*8 = 2048 pipes
    const f32x4 zf = {0.f, 0.f, 0.f, 0.f};
    const int xoff = fr*64 + 4*fg;
    const int nP2 = nPairsTotal >> 1;         // pair-pairs (16384)

    // prologue: prefetch first tile pair
    f32x4 nA0, nA1, nA2, nA3, nB0, nB1, nB2, nB3;
    if (pipe < nP2) {
        const float* xb0 = xg + (size_t)pipe * 2048;
        nA0 = *(const f32x4*)(xb0 + xoff);
        nA1 = *(const f32x4*)(xb0 + xoff + 16);
        nA2 = *(const f32x4*)(xb0 + xoff + 32);
        nA3 = *(const f32x4*)(xb0 + xoff + 48);
        nB0 = *(const f32x4*)(xb0 + 1024 + xoff);
        nB1 = *(const f32x4*)(xb0 + 1024 + xoff + 16);
        nB2 = *(const f32x4*)(xb0 + 1024 + xoff + 32);
        nB3 = *(const f32x4*)(xb0 + 1024 + xoff + 48);
    }

    #pragma unroll 1
    for (int gp2 = pipe; gp2 < nP2; gp2 += 2048) {
        float* obp = out + (size_t)gp2 * 2048;

        f32x4 xA0 = nA0, xA1 = nA1, xA2 = nA2, xA3 = nA3;
        f32x4 xB0 = nB0, xB1 = nB1, xB2 = nB2, xB3 = nB3;

        {   // issue next-tile prefetch; stays in flight across the iteration
            int gpn = gp2 + 2048;
            if (gpn < nP2) {
                const float* xbn = xg + (size_t)gpn * 2048;
                nA0 = *(const f32x4*)(xbn + xoff);
                nA1 = *(const f32x4*)(xbn + xoff + 16);
                nA2 = *(const f32x4*)(xbn + xoff + 32);
                nA3 = *(const f32x4*)(xbn + xoff + 48);
                nB0 = *(const f32x4*)(xbn + 1024 + xoff);
                nB1 = *(const f32x4*)(xbn + 1024 + xoff + 16);
                nB2 = *(const f32x4*)(xbn + 1024 + xoff + 32);
                nB3 = *(const f32x4*)(xbn + 1024 + xoff + 48);
            }
        }
        SB();   // keep prefetch issue pinned early

        #define ACC4(S,SS,V) { S += V[0]+V[1]+V[2]+V[3]; \
                               SS += V[0]*V[0]+V[1]*V[1]+V[2]*V[2]+V[3]*V[3]; }

        // ---- LN1 (shared params) -> h fragments for A and B ----
        bf16x8 hA0, hA1, hB0, hB1;
        {
            float sA=0.f, qA=0.f, sB=0.f, qB=0.f;
            ACC4(sA,qA,xA0); ACC4(sA,qA,xA1); ACC4(sA,qA,xA2); ACC4(sA,qA,xA3);
            ACC4(sB,qB,xB0); ACC4(sB,qB,xB1); ACC4(sB,qB,xB2); ACC4(sB,qB,xB3);
            sA += __shfl_xor(sA,16,64); qA += __shfl_xor(qA,16,64);
            sA += __shfl_xor(sA,32,64); qA += __shfl_xor(qA,32,64);
            sB += __shfl_xor(sB,16,64); qB += __shfl_xor(qB,16,64);
            sB += __shfl_xor(sB,32,64); qB += __shfl_xor(qB,32,64);
            float muA = sA*0.015625f, invA = rsqrtf(qA*0.015625f - muA*muA + 1e-5f);
            float muB = sB*0.015625f, invB = rsqrtf(qB*0.015625f - muB*muB + 1e-5f);
            hA0 = mk8(lnq(xA0,muA,invA,PG4(0),  PG4(64)),
                      lnq(xA1,muA,invA,PG4(16), PG4(80)));
            hA1 = mk8(lnq(xA2,muA,invA,PG4(32), PG4(96)),
                      lnq(xA3,muA,invA,PG4(48), PG4(112)));
            hB0 = mk8(lnq(xB0,muB,invB,PG4(0),  PG4(64)),
                      lnq(xB1,muB,invB,PG4(16), PG4(80)));
            hB1 = mk8(lnq(xB2,muB,invB,PG4(32), PG4(96)),
                      lnq(xB3,muB,invB,PG4(48), PG4(112)));
        }
        // (no fence: attention head-0/1 frag loads may hoist under LN1 VALU)

        // ---- attention: 4 heads; single mid-point fence ----
        uint2 oA0,oA1,oA2,oA3, oB0,oB1,oB2,oB3;
        attn_head2(WFL(0), WFL(1), WFL(8),  WFL(9),  WFL(16), WFL(17),
                   hA0,hA1, hB0,hB1, fr, fg, oA0, oB0);
        attn_head2(WFL(2), WFL(3), WFL(10), WFL(11), WFL(18), WFL(19),
                   hA0,hA1, hB0,hB1, fr, fg, oA1, oB1);
        SB();   // caps transient frag pressure (r18-proven window)
        attn_head2(WFL(4), WFL(5), WFL(12), WFL(13), WFL(20), WFL(21),
                   hA0,hA1, hB0,hB1, fr, fg, oA2, oB2);
        attn_head2(WFL(6), WFL(7), WFL(14), WFL(15), WFL(22), WFL(23),
                   hA0,hA1, hB0,hB1, fr, fg, oA3, oB3);
        // (no fence: proj Wp frag loads may hoist under attn tails)

        // ---- proj: C-init = xv + bp; result becomes new xv (residual 1) ----
        {
            bf16x8 olo = mk8(oA0,oA1), ohi = mk8(oA2,oA3);
            bf16x8 plo = mk8(oB0,oB1), phi = mk8(oB2,oB3);
            #define PROJ(NT, XA, XB) { \
                f32x4 bv = PG4(256 + 16*(NT)); \
                f32x4 ca, cb; \
                ca[0]=XA[0]+bv[0]; ca[1]=XA[1]+bv[1]; ca[2]=XA[2]+bv[2]; ca[3]=XA[3]+bv[3]; \
                cb[0]=XB[0]+bv[0]; cb[1]=XB[1]+bv[1]; cb[2]=XB[2]+bv[2]; cb[3]=XB[3]+bv[3]; \
                bf16x8 wp0 = WFL(24+(NT)*2+0), wp1 = WFL(24+(NT)*2+1); \
                f32x4 pa = MFMA(wp0, olo, ca); pa = MFMA(wp1, ohi, pa); \
                f32x4 pb = MFMA(wp0, plo, cb); pb = MFMA(wp1, phi, pb); \
                XA = pa; XB = pb; }
            PROJ(0, xA0, xB0); PROJ(1, xA1, xB1); PROJ(2, xA2, xB2); PROJ(3, xA3, xB3);
            #undef PROJ
        }
        // (no fence: LN2 VALU may overlap proj MFMAs)

        // ---- LN2 -> h2 frags; then fa C-init = xv + b2 (xv dies here) ----
        bf16x8 cA0, cA1, cB0, cB1;
        f32x4 fA0, fA1, fA2, fA3, fB0, fB1, fB2, fB3;
        {
            float sA=0.f, qA=0.f, sB=0.f, qB=0.f;
            ACC4(sA,qA,xA0); ACC4(sA,qA,xA1); ACC4(sA,qA,xA2); ACC4(sA,qA,xA3);
            ACC4(sB,qB,xB0); ACC4(sB,qB,xB1); ACC4(sB,qB,xB2); ACC4(sB,qB,xB3);
            sA += __shfl_xor(sA,16,64); qA += __shfl_xor(qA,16,64);
            sA += __shfl_xor(sA,32,64); qA += __shfl_xor(qA,32,64);
            sB += __shfl_xor(sB,16,64); qB += __shfl_xor(qB,16,64);
            sB += __shfl_xor(sB,32,64); qB += __shfl_xor(qB,32,64);
            float muA = sA*0.015625f, invA = rsqrtf(qA*0.015625f - muA*muA + 1e-5f);
            float muB = sB*0.015625f, invB = rsqrtf(qB*0.015625f - muB*muB + 1e-5f);
            cA0 = mk8(lnq(xA0,muA,invA,PG4(128), PG4(192)),
                      lnq(xA1,muA,invA,PG4(144), PG4(208)));
            cA1 = mk8(lnq(xA2,muA,invA,PG4(160), PG4(224)),
                      lnq(xA3,muA,invA,PG4(176), PG4(240)));
            cB0 = mk8(lnq(xB0,muB,invB,PG4(128), PG4(192)),
                      lnq(xB1,muB,invB,PG4(144), PG4(208)));
            cB1 = mk8(lnq(xB2,muB,invB,PG4(160), PG4(224)),
                      lnq(xB3,muB,invB,PG4(176), PG4(240)));
            #define FINIT(NT, FA, FB, XA, XB) { \
                f32x4 bv = PG4(320 + 16*(NT)); \
                FA[0]=XA[0]+bv[0]; FA[1]=XA[1]+bv[1]; FA[2]=XA[2]+bv[2]; FA[3]=XA[3]+bv[3]; \
                FB[0]=XB[0]+bv[0]; FB[1]=XB[1]+bv[1]; FB[2]=XB[2]+bv[2]; FB[3]=XB[3]+bv[3]; }
            FINIT(0, fA0, fB0, xA0, xB0); FINIT(1, fA1, fB1, xA1, xB1);
            FINIT(2, fA2, fB2, xA2, xB2); FINIT(3, fA3, fB3, xA3, xB3);
            #undef FINIT
        }
        // (no fence: MLP step-0 W1 frag loads may hoist under LN2 VALU)

        // ---- MLP: W1 C-init = b1; accumulate into fa (already xv+b2).
        //      unroll-1 loop self-fences; no SB inside. ----
        #pragma unroll 1
        for (int m2 = 0; m2 < 8; ++m2) {
            int t0 = 2*m2, t1 = 2*m2 + 1;
            bf16x8 w10 = WFL(32+t0*2+0), w11 = WFL(32+t0*2+1);
            f32x4 bi0 = PG4(384 + 16*t0);
            f32x4 aA = MFMA(w10, cA0, bi0); aA = MFMA(w11, cA1, aA);
            f32x4 aB = MFMA(w10, cB0, bi0); aB = MFMA(w11, cB1, aB);
            uint2 frA0 = relupack0(aA), frB0 = relupack0(aB);
            bf16x8 w12 = WFL(32+t1*2+0), w13 = WFL(32+t1*2+1);
            f32x4 bi1 = PG4(384 + 16*t1);
            f32x4 cAa = MFMA(w12, cA0, bi1); cAa = MFMA(w13, cA1, cAa);
            f32x4 cBa = MFMA(w12, cB0, bi1); cBa = MFMA(w13, cB1, cBa);
            uint2 frA1 = relupack0(cAa), frB1 = relupack0(cBa);
            bf16x8 ffrA = mk8(frA0, frA1), ffrB = mk8(frB0, frB1);
            bf16x8 w20 = WFL(64 + 0*8 + m2);
            fA0 = MFMA(w20, ffrA, fA0); fB0 = MFMA(w20, ffrB, fB0);
            bf16x8 w21 = WFL(64 + 1*8 + m2);
            fA1 = MFMA(w21, ffrA, fA1); fB1 = MFMA(w21, ffrB, fB1);
            bf16x8 w22 = WFL(64 + 2*8 + m2);
            fA2 = MFMA(w22, ffrA, fA2); fB2 = MFMA(w22, ffrB, fB2);
            bf16x8 w23 = WFL(64 + 3*8 + m2);
            fA3 = MFMA(w23, ffrA, fA3); fB3 = MFMA(w23, ffrB, fB3);
        }

        // ---- store (residual+bias already folded into fa) ----
        *(f32x4*)(obp + xoff)             = fA0;
        *(f32x4*)(obp + xoff + 16)        = fA1;
        *(f32x4*)(obp + xoff + 32)        = fA2;
        *(f32x4*)(obp + xoff + 48)        = fA3;
        *(f32x4*)(obp + 1024 + xoff)      = fB0;
        *(f32x4*)(obp + 1024 + xoff + 16) = fB1;
        *(f32x4*)(obp + 1024 + xoff + 32) = fB2;
        *(f32x4*)(obp + 1024 + xoff + 48) = fB3;
        #undef ACC4
    }
    #undef WFL
    #undef PG4
}

extern "C" void kernel_launch(void* const* d_in, const int* in_sizes, int n_in,
                              void* d_out, int out_size, void* d_ws, size_t ws_size,
                              hipStream_t stream) {
    const float* x   = (const float*)d_in[0];
    const float* Wq  = (const float*)d_in[1];
    const float* Wk  = (const float*)d_in[2];
    const float* Wv  = (const float*)d_in[3];
    const float* Wp  = (const float*)d_in[4];
    const float* bp  = (const float*)d_in[5];
    const float* W1  = (const float*)d_in[6];
    const float* b1  = (const float*)d_in[7];
    const float* W2  = (const float*)d_in[8];
    const float* b2  = (const float*)d_in[9];
    const float* g1  = (const float*)d_in[10];
    const float* be1 = (const float*)d_in[11];
    const float* g2  = (const float*)d_in[12];
    const float* be2 = (const float*)d_in[13];
    unsigned short* gw = (unsigned short*)d_ws;   // 100864 bytes used

    pack_weights<<<dim3(98), dim3(512), 0, stream>>>(
        Wq, Wk, Wv, Wp, W1, W2, bp, b1, b2, g1, be1, g2, be2, gw);

    int nPairs = in_sizes[0] / 1024;   // (B*T*C) / (2*8*64) = 32768
    fused_block<<<dim3(256), dim3(512), 0, stream>>>(
        gw, x, (float*)d_out, nPairs);
}